// Round 25
// baseline (35.209 us; speedup 1.0000x reference)
//
#include <hip/hip_runtime.h>

// LDDMM variational evolve: N-body Gaussian kernel sums, N=8192, D=3, fp32.
// dmom_i = (1/SIG2) * sum_j K_ij * <mom_i,mom_j> * (pos_i - pos_j)
// dpos_i = sum_j K_ij * mom_j
// K_ij = exp(-||xi-xj||^2/(2*SIG2)), SIG2=0.01 -> exp2(-72.1348*d2)
//
// Cell list: K < 4e-6 for d2 > 0.25; dropped-pair error ~1e-2 << thr 2.36.
// Ladder: brute 49.1 -> 36.5 -> 29.9 -> 24.9 -> 23.9 -> 23.5 (R24 DPP).
// R25: (1) 1-deep SOFTWARE PREFETCH in main's gather loop -- addresses are
// iteration-independent (f + SGPR table), so issue iter i+1's 2 loads
// before evaluating iter i: halves exposed L2 latency at 8 waves/SIMD.
// (2) histogram split into 8 blocks of LDS sub-histograms writing
// NON-ATOMIC partials [cell][block]; scan sums 8 partials via contiguous
// int4 reads. No global atomics (R16 killer), no grid barrier (R17 killer).
// R7 NaN lesson: ci stays inside the exponent (arg <= 0 always).
// exp = __builtin_amdgcn_exp2f (plain exp2f -> OCML fixup; R2 measured).

#define NPTS  8192
#define NCXY  16
#define NCZ   32
#define NCELL (NCXY * NCXY * NCZ)   // 8192
#define NHB   8                     // histogram blocks
#define ORIGIN    (-4.0f)
#define EDGE      0.5f
#define INV_EDGE  2.0f              // xy edge 0.5
#define INV_EDGEZ 4.0f              // z slab 0.25
#define RCUT2     0.25f

#define A_DOT 144.269504088896f     // 2*50*log2(e)
#define INV_ADOT (1.0f / 144.269504088896f)
#define A_R   (-72.134752044448f)   // -50*log2(e)
#define INV_SIG2 100.0f

#define EXP2(x) __builtin_amdgcn_exp2f(x)

__device__ __forceinline__ int clampi(int c, int hi) { return min(max(c, 0), hi); }

__device__ __forceinline__ int cell_of(float x, float y, float z) {
    const int cx = clampi((int)floorf((x - ORIGIN) * INV_EDGE),  NCXY - 1);
    const int cy = clampi((int)floorf((y - ORIGIN) * INV_EDGE),  NCXY - 1);
    const int cz = clampi((int)floorf((z - ORIGIN) * INV_EDGEZ), NCZ  - 1);
    return (cx * NCXY + cy) * NCZ + cz;
}

// ---- DPP wave64 sum (VALU only, no LDS pipe). Valid result in lane 63. ----
template <int CTRL, int ROW, int BANK>
__device__ __forceinline__ float dpp_add(float x) {
    const int r = __builtin_amdgcn_update_dpp(0, __float_as_int(x),
                                              CTRL, ROW, BANK, false);
    return x + __int_as_float(r);
}
__device__ __forceinline__ float wave64_sum(float x) {
    x = dpp_add<0x111, 0xf, 0xf>(x);   // row_shr:1
    x = dpp_add<0x112, 0xf, 0xf>(x);   // row_shr:2
    x = dpp_add<0x114, 0xf, 0xe>(x);   // row_shr:4
    x = dpp_add<0x118, 0xf, 0xc>(x);   // row_shr:8
    x = dpp_add<0x142, 0xa, 0xf>(x);   // row_bcast:15
    x = dpp_add<0x143, 0xc, 0xf>(x);   // row_bcast:31
    return x;                           // lane 63 = full-wave sum
}

// ---- prep 1: 8-block LDS sub-histograms, non-atomic partials [cell][NHB] ----
__global__ __launch_bounds__(1024)
void k_hist8(const float* __restrict__ pos, int* __restrict__ partial)
{
    __shared__ int cnt[NCELL];      // 32 KB
    const int b = blockIdx.x;       // 0..7
    const int t = threadIdx.x;

    #pragma unroll
    for (int k = 0; k < NCELL / 1024; ++k) cnt[t + k * 1024] = 0;
    __syncthreads();

    const int i = b * 1024 + t;     // one point per thread
    atomicAdd(&cnt[cell_of(pos[3*i+0], pos[3*i+1], pos[3*i+2])], 1);
    __syncthreads();

    #pragma unroll
    for (int k = 0; k < NCELL / 1024; ++k) {
        const int c = t + k * 1024;
        partial[c * NHB + b] = cnt[c];
    }
}

// ---- prep 2: sum partials + scan 8192 bins, one block ----
__global__ __launch_bounds__(1024)
void k_scan(const int* __restrict__ partial,
            int* __restrict__ start, int* __restrict__ cur)
{
    __shared__ int wtot[16];
    __shared__ int wexcl[16];
    const int t = threadIdx.x;
    const int lane = t & 63;
    const int wid = t >> 6;

    // thread t owns cells 8t..8t+7; partial rows are contiguous:
    // int4 indices 16t..16t+15 (fully coalesced).
    const int4* pp = reinterpret_cast<const int4*>(partial);
    int cnt8[8];
    #pragma unroll
    for (int k = 0; k < 8; ++k) {
        const int4 a = pp[16 * t + 2 * k + 0];
        const int4 b = pp[16 * t + 2 * k + 1];
        cnt8[k] = a.x + a.y + a.z + a.w + b.x + b.y + b.z + b.w;
    }

    int pre[8];
    int s = 0;
    #pragma unroll
    for (int k = 0; k < 8; ++k) { pre[k] = s; s += cnt8[k]; }
    int p = s;
    #pragma unroll
    for (int off = 1; off < 64; off <<= 1) {
        const int v = __shfl_up(p, off);
        if (lane >= off) p += v;
    }
    if (lane == 63) wtot[wid] = p;
    __syncthreads();
    if (t < 16) {
        const int w = wtot[t];
        int q = w;
        #pragma unroll
        for (int off = 1; off < 16; off <<= 1) {
            const int v = __shfl_up(q, off);
            if (t >= off) q += v;
        }
        wexcl[t] = q - w;
    }
    __syncthreads();
    const int base = wexcl[wid] + (p - s);
    #pragma unroll
    for (int k = 0; k < 8; ++k) {
        const int v = base + pre[k];
        start[8*t + k] = v;
        cur[8*t + k] = v;
    }
    if (t == 0) start[NCELL] = NPTS;
}

// ---------------- prep 3: scatter (parallel, atomic cursor ranks) ----------------
__global__ __launch_bounds__(256)
void k_scatter(const float* __restrict__ mom, const float* __restrict__ pos,
               int* __restrict__ cur,
               float* __restrict__ pmP, float* __restrict__ pmM,
               int* __restrict__ inv)
{
    const int i = blockIdx.x * 256 + threadIdx.x;
    const float x = pos[3*i+0], y = pos[3*i+1], z = pos[3*i+2];
    const int dst = atomicAdd(&cur[cell_of(x, y, z)], 1);
    const float r2 = x*x + y*y + z*z;
    reinterpret_cast<float4*>(pmP)[dst] = make_float4(A_DOT*x, A_DOT*y, A_DOT*z, A_R*r2);
    reinterpret_cast<float4*>(pmM)[dst] = make_float4(mom[3*i+0], mom[3*i+1], mom[3*i+2], 0.0f);
    inv[dst] = i;
}

// ---- main: one wave/block per point, flattened stream, 1-deep prefetch ----
__global__ __launch_bounds__(64)
void k_main(const float* __restrict__ pmP, const float* __restrict__ pmM,
            const int* __restrict__ inv, const int* __restrict__ start,
            float* __restrict__ out)
{
    const int wid  = blockIdx.x;                              // sorted idx 0..8191
    const int lane = threadIdx.x;                             // 0..63

    const float4* __restrict__ pmPv = reinterpret_cast<const float4*>(pmP);
    const float4* __restrict__ pmMv = reinterpret_cast<const float4*>(pmM);

    // i-data: 2 uniform 16B loads from the SORTED arrays (ci = Pi.w).
    const float4 Pi = pmPv[wid];
    const float4 Mi = pmMv[wid];
    const float xi = Pi.x * INV_ADOT, yi = Pi.y * INV_ADOT, zi = Pi.z * INV_ADOT;
    const float pxi = Mi.x, pyi = Mi.y, pzi = Mi.z;
    const float ci  = Pi.w;

    const int cx = clampi((int)floorf((xi - ORIGIN) * INV_EDGE), NCXY - 1);
    const int cy = clampi((int)floorf((yi - ORIGIN) * INV_EDGE), NCXY - 1);

    // Lanes 0..8: fixed 3x3 columns, z-clipped range (st,len); pruned -> len 0.
    int st_l = 0, len_l = 0;
    if (lane < 9) {
        const int nx = cx + (lane / 3) - 1;
        const int ny = cy + (lane % 3) - 1;
        if (nx >= 0 && nx < NCXY && ny >= 0 && ny < NCXY) {
            const float X0 = ORIGIN + nx * EDGE;
            const float Y0 = ORIGIN + ny * EDGE;
            const float dx = fmaxf(fmaxf(X0 - xi, xi - (X0 + EDGE)), 0.0f);
            const float dy = fmaxf(fmaxf(Y0 - yi, yi - (Y0 + EDGE)), 0.0f);
            const float m2 = dx * dx + dy * dy;
            if (m2 <= RCUT2) {
                const float zr = __builtin_sqrtf(RCUT2 - m2);
                const int z0 = clampi((int)floorf((zi - zr - ORIGIN) * INV_EDGEZ), NCZ - 1);
                const int z1 = clampi((int)floorf((zi + zr - ORIGIN) * INV_EDGEZ), NCZ - 1);
                const int base = (nx * NCXY + ny) * NCZ;
                st_l  = start[base + z0];
                len_l = start[base + z1 + 1] - st_l;
            }
        }
    }

    // Wave-uniform tables via readlane (SALU); scalar prefix.
    int p0[9], ofs[9];
    int run = 0;
    #pragma unroll
    for (int q = 0; q < 9; ++q) {
        const int ln = __builtin_amdgcn_readlane(len_l, q);
        const int st = __builtin_amdgcn_readlane(st_l, q);
        p0[q]  = run;
        ofs[q] = st - run;
        run   += ln;
    }
    const int T = run;                 // total virtual stream length

    float S = 0.f, SPx = 0.f, SPy = 0.f, SPz = 0.f;
    float apx = 0.f, apy = 0.f, apz = 0.f;

    // Prologue: load iteration 0 (clamped; safe even when T == 0).
    int f = lane;
    int osel = ofs[0];
    #pragma unroll
    for (int q = 1; q < 9; ++q) osel = (f >= p0[q]) ? ofs[q] : osel;
    int j = min(f + osel, NPTS - 1);
    float4 P = pmPv[j];
    float4 M = pmMv[j];

    for (int f0 = 0; f0 < T; f0 += 64) {
        // Prefetch iteration i+1 (addresses independent of current compute).
        const int fn = f0 + 64 + lane;
        int oseln = ofs[0];
        #pragma unroll
        for (int q = 1; q < 9; ++q) oseln = (fn >= p0[q]) ? ofs[q] : oseln;
        const int jn = min(fn + oseln, NPTS - 1);
        const float4 Pn = pmPv[jn];
        const float4 Mn = pmMv[jn];

        if (f0 + lane < T) {
            // arg = ci + A_DOT*<xi,xj> + A_R*rj2 = -72.13*d2 <= 0 (no overflow)
            float arg = __builtin_fmaf(zi, P.z, ci + P.w);
            arg = __builtin_fmaf(yi, P.y, arg);
            arg = __builtin_fmaf(xi, P.x, arg);
            const float K = EXP2(arg);
            const float C = __builtin_fmaf(pzi, M.z,
                              __builtin_fmaf(pyi, M.y, pxi * M.x));
            const float s = K * C;
            S += s;
            SPx = __builtin_fmaf(s, P.x, SPx);
            SPy = __builtin_fmaf(s, P.y, SPy);
            SPz = __builtin_fmaf(s, P.z, SPz);
            apx = __builtin_fmaf(K, M.x, apx);
            apy = __builtin_fmaf(K, M.y, apy);
            apz = __builtin_fmaf(K, M.z, apz);
        }
        P = Pn; M = Mn;
    }

    // DPP wave64 reduction (VALU pipe); results valid in lane 63.
    S   = wave64_sum(S);
    SPx = wave64_sum(SPx);
    SPy = wave64_sum(SPy);
    SPz = wave64_sum(SPz);
    apx = wave64_sum(apx);
    apy = wave64_sum(apy);
    apz = wave64_sum(apz);

    if (lane == 63) {
        const int oi = inv[wid];      // original index, output addressing only
        const float us = INV_SIG2 / A_DOT;
        out[3*oi+0] = INV_SIG2 * xi * S - us * SPx;
        out[3*oi+1] = INV_SIG2 * yi * S - us * SPy;
        out[3*oi+2] = INV_SIG2 * zi * S - us * SPz;
        out[3*NPTS + 3*oi+0] = apx;
        out[3*NPTS + 3*oi+1] = apy;
        out[3*NPTS + 3*oi+2] = apz;
    }
}

extern "C" void kernel_launch(void* const* d_in, const int* in_sizes, int n_in,
                              void* d_out, int out_size, void* d_ws, size_t ws_size,
                              hipStream_t stream)
{
    const float* mom = (const float*)d_in[0];
    const float* pos = (const float*)d_in[1];
    float* out = (float*)d_out;

    // ws layout: pmP (4*NPTS f), pmM (4*NPTS f), inv (NPTS i),
    //            start (NCELL+1 i), cur (NCELL i), partial (NCELL*NHB i)
    float* pmP   = (float*)d_ws;
    float* pmM   = pmP + (size_t)4 * NPTS;
    int* inv     = (int*)(pmM + (size_t)4 * NPTS);
    int* start   = inv + NPTS;
    int* cur     = start + NCELL + 1;
    int* partial = cur + NCELL;

    k_hist8<<<NHB, 1024, 0, stream>>>(pos, partial);
    k_scan<<<1, 1024, 0, stream>>>(partial, start, cur);
    k_scatter<<<NPTS / 256, 256, 0, stream>>>(mom, pos, cur, pmP, pmM, inv);
    k_main<<<NPTS, 64, 0, stream>>>(pmP, pmM, inv, start, out);
}

// Round 26
// 23.308 us; speedup vs baseline: 1.5106x; 1.5106x over previous
//
#include <hip/hip_runtime.h>

// LDDMM variational evolve: N-body Gaussian kernel sums, N=8192, D=3, fp32.
// dmom_i = (1/SIG2) * sum_j K_ij * <mom_i,mom_j> * (pos_i - pos_j)
// dpos_i = sum_j K_ij * mom_j
// K_ij = exp(-||xi-xj||^2/(2*SIG2)), SIG2=0.01 -> exp2(-72.1348*d2)
//
// FINAL = R24 (measured best 23.5us, absmax 0.25; 2.1x vs brute-force 49.1).
// Cell list: K < 4e-6 for d2 > 0.25; dropped-pair error ~1e-2 << thr 2.36.
// Ladder: brute 49.1 -> cell list 36.5 -> z-merged columns 29.9 -> z-clip +
// 3 dispatches 24.9 -> flattened virtual j-stream 23.9 -> DPP/readlane
// cross-lane (DS-free) 23.5. Attacks that REGRESSED (kept for the record):
// tile-union R11 +29; pair-share R14 +1.2; global-atomic hist R16 +9 (hot
// cell = same-address L2 atomic chain); spin grid-barrier R17 +85 (spin
// starves L2); fused 1-block prep R19 +11 (single-CU scatter); 32-lane
// groups + strided map R20 +3.9 (occupancy+locality); balance permutation
// + 32B interleave R22 +1.5; software prefetch + hist split R25 +11.7
// (doubled addr-cascade VALU; implicit 8-wave/SIMD overlap already hides
// latency). Floor = per-wave fixed cost + single-CU hist + ~3 dispatch
// boundaries; NOT a HW roofline (VALUBusy <10%, HBM <1%).
// R7 NaN lesson: ci stays inside the exponent (arg <= 0 always).
// exp = __builtin_amdgcn_exp2f (plain exp2f -> OCML fixup; R2 measured).

#define NPTS  8192
#define NCXY  16
#define NCZ   32
#define NCELL (NCXY * NCXY * NCZ)   // 8192
#define ORIGIN    (-4.0f)
#define EDGE      0.5f
#define INV_EDGE  2.0f              // xy edge 0.5
#define INV_EDGEZ 4.0f              // z slab 0.25
#define RCUT2     0.25f

#define A_DOT 144.269504088896f     // 2*50*log2(e)
#define INV_ADOT (1.0f / 144.269504088896f)
#define A_R   (-72.134752044448f)   // -50*log2(e)
#define INV_SIG2 100.0f

#define EXP2(x) __builtin_amdgcn_exp2f(x)

__device__ __forceinline__ int clampi(int c, int hi) { return min(max(c, 0), hi); }

__device__ __forceinline__ int cell_of(float x, float y, float z) {
    const int cx = clampi((int)floorf((x - ORIGIN) * INV_EDGE),  NCXY - 1);
    const int cy = clampi((int)floorf((y - ORIGIN) * INV_EDGE),  NCXY - 1);
    const int cz = clampi((int)floorf((z - ORIGIN) * INV_EDGEZ), NCZ  - 1);
    return (cx * NCXY + cy) * NCZ + cz;
}

// ---- DPP wave64 sum (VALU only, no LDS pipe). Valid result in lane 63. ----
template <int CTRL, int ROW, int BANK>
__device__ __forceinline__ float dpp_add(float x) {
    const int r = __builtin_amdgcn_update_dpp(0, __float_as_int(x),
                                              CTRL, ROW, BANK, false);
    return x + __int_as_float(r);
}
__device__ __forceinline__ float wave64_sum(float x) {
    x = dpp_add<0x111, 0xf, 0xf>(x);   // row_shr:1
    x = dpp_add<0x112, 0xf, 0xf>(x);   // row_shr:2
    x = dpp_add<0x114, 0xf, 0xe>(x);   // row_shr:4
    x = dpp_add<0x118, 0xf, 0xc>(x);   // row_shr:8
    x = dpp_add<0x142, 0xa, 0xf>(x);   // row_bcast:15
    x = dpp_add<0x143, 0xc, 0xf>(x);   // row_bcast:31
    return x;                           // lane 63 = full-wave sum
}

// ---------------- prep 1: count (LDS hist, vec loads) + scan, one block ----------------
__global__ __launch_bounds__(1024)
void k_countscan(const float* __restrict__ pos,
                 int* __restrict__ start, int* __restrict__ cur)
{
    __shared__ int cnt[NCELL];      // 32 KB
    __shared__ int wtot[16];
    __shared__ int wexcl[16];
    const int t = threadIdx.x;
    const int lane = t & 63;
    const int wid = t >> 6;

    #pragma unroll
    for (int k = 0; k < NCELL / 1024; ++k) cnt[t + k * 1024] = 0;
    __syncthreads();

    // histogram: thread t owns points 8t..8t+7, read as 6 x float4 (96 B)
    {
        const float4* pv = reinterpret_cast<const float4*>(pos) + 6 * t;
        float4 v0 = pv[0], v1 = pv[1], v2 = pv[2];
        float4 v3 = pv[3], v4 = pv[4], v5 = pv[5];
        const float px[8] = {v0.x, v0.w, v1.z, v2.y, v3.x, v3.w, v4.z, v5.y};
        const float py[8] = {v0.y, v1.x, v1.w, v2.z, v3.y, v4.x, v4.w, v5.z};
        const float pz[8] = {v0.z, v1.y, v2.x, v2.w, v3.z, v4.y, v5.x, v5.w};
        #pragma unroll
        for (int k = 0; k < 8; ++k)
            atomicAdd(&cnt[cell_of(px[k], py[k], pz[k])], 1);
    }
    __syncthreads();

    // scan 8192 bins: thread t owns cells 8t..8t+7
    int pre[8];
    int s = 0;
    #pragma unroll
    for (int k = 0; k < 8; ++k) { pre[k] = s; s += cnt[8*t + k]; }
    int p = s;
    #pragma unroll
    for (int off = 1; off < 64; off <<= 1) {
        const int v = __shfl_up(p, off);
        if (lane >= off) p += v;
    }
    if (lane == 63) wtot[wid] = p;
    __syncthreads();
    if (t < 16) {
        const int w = wtot[t];
        int q = w;
        #pragma unroll
        for (int off = 1; off < 16; off <<= 1) {
            const int v = __shfl_up(q, off);
            if (t >= off) q += v;
        }
        wexcl[t] = q - w;
    }
    __syncthreads();
    const int base = wexcl[wid] + (p - s);
    #pragma unroll
    for (int k = 0; k < 8; ++k) {
        const int v = base + pre[k];
        start[8*t + k] = v;
        cur[8*t + k] = v;
    }
    if (t == 0) start[NCELL] = NPTS;
}

// ---------------- prep 2: scatter (parallel, atomic cursor ranks) ----------------
__global__ __launch_bounds__(256)
void k_scatter(const float* __restrict__ mom, const float* __restrict__ pos,
               int* __restrict__ cur,
               float* __restrict__ pmP, float* __restrict__ pmM,
               int* __restrict__ inv)
{
    const int i = blockIdx.x * 256 + threadIdx.x;
    const float x = pos[3*i+0], y = pos[3*i+1], z = pos[3*i+2];
    const int dst = atomicAdd(&cur[cell_of(x, y, z)], 1);
    const float r2 = x*x + y*y + z*z;
    reinterpret_cast<float4*>(pmP)[dst] = make_float4(A_DOT*x, A_DOT*y, A_DOT*z, A_R*r2);
    reinterpret_cast<float4*>(pmM)[dst] = make_float4(mom[3*i+0], mom[3*i+1], mom[3*i+2], 0.0f);
    inv[dst] = i;
}

// ------- main: one wave/block per point, flattened stream, DS-free cross-lane -------
__global__ __launch_bounds__(64)
void k_main(const float* __restrict__ pmP, const float* __restrict__ pmM,
            const int* __restrict__ inv, const int* __restrict__ start,
            float* __restrict__ out)
{
    const int wid  = blockIdx.x;                              // sorted idx 0..8191
    const int lane = threadIdx.x;                             // 0..63

    const float4* __restrict__ pmPv = reinterpret_cast<const float4*>(pmP);
    const float4* __restrict__ pmMv = reinterpret_cast<const float4*>(pmM);

    // i-data: 2 uniform 16B loads from the SORTED arrays (ci = Pi.w).
    const float4 Pi = pmPv[wid];
    const float4 Mi = pmMv[wid];
    const float xi = Pi.x * INV_ADOT, yi = Pi.y * INV_ADOT, zi = Pi.z * INV_ADOT;
    const float pxi = Mi.x, pyi = Mi.y, pzi = Mi.z;
    const float ci  = Pi.w;

    const int cx = clampi((int)floorf((xi - ORIGIN) * INV_EDGE), NCXY - 1);
    const int cy = clampi((int)floorf((yi - ORIGIN) * INV_EDGE), NCXY - 1);

    // Lanes 0..8: fixed 3x3 columns, z-clipped range (st,len); pruned -> len 0.
    int st_l = 0, len_l = 0;
    if (lane < 9) {
        const int nx = cx + (lane / 3) - 1;
        const int ny = cy + (lane % 3) - 1;
        if (nx >= 0 && nx < NCXY && ny >= 0 && ny < NCXY) {
            const float X0 = ORIGIN + nx * EDGE;
            const float Y0 = ORIGIN + ny * EDGE;
            const float dx = fmaxf(fmaxf(X0 - xi, xi - (X0 + EDGE)), 0.0f);
            const float dy = fmaxf(fmaxf(Y0 - yi, yi - (Y0 + EDGE)), 0.0f);
            const float m2 = dx * dx + dy * dy;
            if (m2 <= RCUT2) {
                const float zr = __builtin_sqrtf(RCUT2 - m2);
                const int z0 = clampi((int)floorf((zi - zr - ORIGIN) * INV_EDGEZ), NCZ - 1);
                const int z1 = clampi((int)floorf((zi + zr - ORIGIN) * INV_EDGEZ), NCZ - 1);
                const int base = (nx * NCXY + ny) * NCZ;
                st_l  = start[base + z0];
                len_l = start[base + z1 + 1] - st_l;
            }
        }
    }

    // Wave-uniform tables via readlane (SALU, no DS pipe); scalar prefix.
    int p0[9], ofs[9];
    int run = 0;
    #pragma unroll
    for (int q = 0; q < 9; ++q) {
        const int ln = __builtin_amdgcn_readlane(len_l, q);
        const int st = __builtin_amdgcn_readlane(st_l, q);
        p0[q]  = run;
        ofs[q] = st - run;
        run   += ln;
    }
    const int T = run;                 // total virtual stream length

    float S = 0.f, SPx = 0.f, SPy = 0.f, SPz = 0.f;
    float apx = 0.f, apy = 0.f, apz = 0.f;

    for (int f0 = 0; f0 < T; f0 += 64) {
        const int f = f0 + lane;
        // column select: largest q with p0[q] <= f (SGPR operands)
        int off_sel = ofs[0];
        #pragma unroll
        for (int q = 1; q < 9; ++q)
            off_sel = (f >= p0[q]) ? ofs[q] : off_sel;
        if (f < T) {
            const int j = f + off_sel;
            const float4 P = pmPv[j];     // segmented-coalesced
            const float4 M = pmMv[j];
            // arg = ci + A_DOT*<xi,xj> + A_R*rj2 = -72.13*d2 <= 0 (no overflow)
            float arg = __builtin_fmaf(zi, P.z, ci + P.w);
            arg = __builtin_fmaf(yi, P.y, arg);
            arg = __builtin_fmaf(xi, P.x, arg);
            const float K = EXP2(arg);
            const float C = __builtin_fmaf(pzi, M.z,
                              __builtin_fmaf(pyi, M.y, pxi * M.x));
            const float s = K * C;
            S += s;
            SPx = __builtin_fmaf(s, P.x, SPx);
            SPy = __builtin_fmaf(s, P.y, SPy);
            SPz = __builtin_fmaf(s, P.z, SPz);
            apx = __builtin_fmaf(K, M.x, apx);
            apy = __builtin_fmaf(K, M.y, apy);
            apz = __builtin_fmaf(K, M.z, apz);
        }
    }

    // DPP wave64 reduction (VALU pipe); results valid in lane 63.
    S   = wave64_sum(S);
    SPx = wave64_sum(SPx);
    SPy = wave64_sum(SPy);
    SPz = wave64_sum(SPz);
    apx = wave64_sum(apx);
    apy = wave64_sum(apy);
    apz = wave64_sum(apz);

    if (lane == 63) {
        const int oi = inv[wid];      // original index, output addressing only
        const float us = INV_SIG2 / A_DOT;
        out[3*oi+0] = INV_SIG2 * xi * S - us * SPx;
        out[3*oi+1] = INV_SIG2 * yi * S - us * SPy;
        out[3*oi+2] = INV_SIG2 * zi * S - us * SPz;
        out[3*NPTS + 3*oi+0] = apx;
        out[3*NPTS + 3*oi+1] = apy;
        out[3*NPTS + 3*oi+2] = apz;
    }
}

extern "C" void kernel_launch(void* const* d_in, const int* in_sizes, int n_in,
                              void* d_out, int out_size, void* d_ws, size_t ws_size,
                              hipStream_t stream)
{
    const float* mom = (const float*)d_in[0];
    const float* pos = (const float*)d_in[1];
    float* out = (float*)d_out;

    // ws layout: pmP (4*NPTS f), pmM (4*NPTS f), inv (NPTS i),
    //            start (NCELL+1 i), cur (NCELL i)  -> ~355 KB
    float* pmP  = (float*)d_ws;
    float* pmM  = pmP + (size_t)4 * NPTS;
    int* inv    = (int*)(pmM + (size_t)4 * NPTS);
    int* start  = inv + NPTS;
    int* cur    = start + NCELL + 1;

    k_countscan<<<1, 1024, 0, stream>>>(pos, start, cur);
    k_scatter<<<NPTS / 256, 256, 0, stream>>>(mom, pos, cur, pmP, pmM, inv);
    k_main<<<NPTS, 64, 0, stream>>>(pmP, pmM, inv, start, out);
}